// Round 1
// baseline (1908.798 us; speedup 1.0000x reference)
//
#include <hip/hip_runtime.h>
#include <stdint.h>

// ---- problem constants ----
#define WIN_N 49
#define NH 16
#define HD 32
#define CDIM 512
#define NB 4096
#define M_ROWS (NB * WIN_N)        // 200704 = 128 * 1568 exactly
#define QKV_N 1536
#define SCALE_Q 0.17677669529663689f  // 32^-0.5

typedef __attribute__((ext_vector_type(8))) short bf16x8;
typedef __attribute__((ext_vector_type(4))) float f32x4;

__device__ __forceinline__ unsigned short f2bf(float f) {
  unsigned int u = __float_as_uint(f);
  u += 0x7fff + ((u >> 16) & 1);   // RNE
  return (unsigned short)(u >> 16);
}
__device__ __forceinline__ unsigned int pack2(float a, float b) {
  return (unsigned int)f2bf(a) | ((unsigned int)f2bf(b) << 16);
}

// ---- kernel 1: transpose + bf16-convert weights: wT[n][k] = w[k][n] ----
__global__ void prep_weights(const float* __restrict__ qkv_w,
                             const float* __restrict__ proj_w,
                             unsigned short* __restrict__ wqkv_t,
                             unsigned short* __restrict__ wproj_t) {
  int i = blockIdx.x * blockDim.x + threadIdx.x;
  if (i < QKV_N * CDIM) {                 // 786432: [1536][512]
    int n = i >> 9, k = i & 511;
    wqkv_t[i] = f2bf(qkv_w[k * QKV_N + n]);
  } else {
    int j = i - QKV_N * CDIM;
    if (j < CDIM * CDIM) {                // 262144: [512][512]
      int n = j >> 9, k = j & 511;
      wproj_t[j] = f2bf(proj_w[k * CDIM + n]);
    }
  }
}

// ---- kernel 2/4: C[M][N] = A[M][K] * Bt[N][K]^T, 128x128 tile, BK=32 ----
// 4 waves in 2x2; each wave: 4x4 grid of 16x16x32 bf16 MFMAs.
template <bool A_F32, bool OUT_F32>
__global__ __launch_bounds__(256) void gemm_bt(
    const void* __restrict__ Aptr, int lda,
    const unsigned short* __restrict__ Bt,
    void* __restrict__ Cptr, int ldc,
    const float* __restrict__ bias,
    int K, int scale_cols, float scale) {
  __shared__ __align__(16) unsigned short As[128 * 32];
  __shared__ __align__(16) unsigned short Bs[128 * 32];
  const int tid = threadIdx.x;
  const int bm = blockIdx.y * 128;
  const int bn = blockIdx.x * 128;
  const int lane = tid & 63, wid = tid >> 6;
  const int wm = (wid & 1) * 64, wn = (wid >> 1) * 64;
  const int quad = lane >> 4, l16 = lane & 15;
  const int r0 = tid >> 2;          // staging row 0..63 (and +64)
  const int c0 = (tid & 3) * 8;     // staging col {0,8,16,24}

  const f32x4 fzero = {0.f, 0.f, 0.f, 0.f};
  f32x4 acc[4][4];
#pragma unroll
  for (int i = 0; i < 4; i++)
#pragma unroll
    for (int j = 0; j < 4; j++) acc[i][j] = fzero;

  const float* Af = (const float*)Aptr;
  const unsigned short* Ab = (const unsigned short*)Aptr;

  for (int kk = 0; kk < K; kk += 32) {
    if constexpr (A_F32) {
      const float* p0 = Af + (size_t)(bm + r0) * lda + kk + c0;
      const float* p1 = p0 + (size_t)64 * lda;
      float4 x0 = *(const float4*)p0;
      float4 x1 = *(const float4*)(p0 + 4);
      float4 y0 = *(const float4*)p1;
      float4 y1 = *(const float4*)(p1 + 4);
      *(uint4*)&As[r0 * 32 + c0] =
          make_uint4(pack2(x0.x, x0.y), pack2(x0.z, x0.w), pack2(x1.x, x1.y), pack2(x1.z, x1.w));
      *(uint4*)&As[(r0 + 64) * 32 + c0] =
          make_uint4(pack2(y0.x, y0.y), pack2(y0.z, y0.w), pack2(y1.x, y1.y), pack2(y1.z, y1.w));
    } else {
      const unsigned short* p0 = Ab + (size_t)(bm + r0) * lda + kk + c0;
      *(uint4*)&As[r0 * 32 + c0] = *(const uint4*)p0;
      *(uint4*)&As[(r0 + 64) * 32 + c0] = *(const uint4*)(p0 + (size_t)64 * lda);
    }
    {
      const unsigned short* q0 = Bt + (size_t)(bn + r0) * K + kk + c0;
      *(uint4*)&Bs[r0 * 32 + c0] = *(const uint4*)q0;
      *(uint4*)&Bs[(r0 + 64) * 32 + c0] = *(const uint4*)(q0 + (size_t)64 * K);
    }
    __syncthreads();
    bf16x8 a[4], b[4];
#pragma unroll
    for (int i = 0; i < 4; i++) a[i] = *(const bf16x8*)&As[(wm + i * 16 + l16) * 32 + quad * 8];
#pragma unroll
    for (int i = 0; i < 4; i++) b[i] = *(const bf16x8*)&Bs[(wn + i * 16 + l16) * 32 + quad * 8];
#pragma unroll
    for (int i = 0; i < 4; i++)
#pragma unroll
      for (int j = 0; j < 4; j++)
        acc[i][j] = __builtin_amdgcn_mfma_f32_16x16x32_bf16(a[i], b[j], acc[i][j], 0, 0, 0);
    __syncthreads();
  }

  // epilogue: D row = quad*4+reg, col = lane&15 (m89/m91 verified)
#pragma unroll
  for (int i = 0; i < 4; i++) {
    const int row = bm + wm + i * 16 + quad * 4;
#pragma unroll
    for (int j = 0; j < 4; j++) {
      const int col = bn + wn + j * 16 + l16;
      const float bv = bias[col];
      const float sc = (col < scale_cols) ? scale : 1.0f;
#pragma unroll
      for (int r = 0; r < 4; r++) {
        float v = (acc[i][j][r] + bv) * sc;
        if constexpr (OUT_F32)
          ((float*)Cptr)[(size_t)(row + r) * ldc + col] = v;
        else
          ((unsigned short*)Cptr)[(size_t)(row + r) * ldc + col] = f2bf(v);
      }
    }
  }
}

// ---- kernel 3: fused window attention, one wave per (window, head) ----
// qkv layout: [M_ROWS][1536] bf16; cols 0..511=Q*scale (head-major), 512..1023=K, 1024..1535=V.
// Output O overwrites this head's Q columns (disjoint across heads -> race-free).
__global__ __launch_bounds__(256) void attn_mfma(
    unsigned short* __restrict__ qkv,
    const float* __restrict__ bias_table,   // [169][16]
    const float* __restrict__ mask) {       // [64][49][49]
  const int PS = 72;  // P row stride (elems): 16B-aligned rows, good bank spread
  const int VS = 64;  // Vt row stride
  __shared__ __align__(16) unsigned short Pl_all[4][64 * 72];  // 36864 B
  __shared__ __align__(16) unsigned short Vt_all[4][32 * 64];  // 16384 B
  const int tid = threadIdx.x;
  const int wid = tid >> 6, lane = tid & 63;
  const int quad = lane >> 4, l16 = lane & 15;
  const int b = blockIdx.x;
  const int h = blockIdx.y * 4 + wid;
  unsigned short* Pl = Pl_all[wid];
  unsigned short* Vt = Vt_all[wid];
  const size_t row0 = (size_t)b * WIN_N;

  // Q (A-operand) and K (B-operand) fragments direct from global:
  // frag element k-dim = quad*8+j is contiguous 16B in memory.
  bf16x8 aq[4], bk[4];
#pragma unroll
  for (int i = 0; i < 4; i++) {
    size_t r = row0 + i * 16 + l16;
    if (r > (size_t)(M_ROWS - 1)) r = M_ROWS - 1;  // clamp: garbage rows only feed t>=49 / m>=49
    const unsigned short* pq = qkv + r * QKV_N + h * HD + quad * 8;
    aq[i] = *(const bf16x8*)pq;
    bk[i] = *(const bf16x8*)(pq + 512);
  }

  // V^T into LDS: Vt[d][m]; zero the m>=49 pad (0 * garbage would NaN otherwise)
  {
    const int m = lane;
    if (m < WIN_N) {
      const unsigned short* pv = qkv + (row0 + m) * QKV_N + 1024 + h * HD;
      uint4 tv[4];
      tv[0] = *(const uint4*)(pv + 0);
      tv[1] = *(const uint4*)(pv + 8);
      tv[2] = *(const uint4*)(pv + 16);
      tv[3] = *(const uint4*)(pv + 24);
      const unsigned short* tmp = (const unsigned short*)tv;
#pragma unroll
      for (int d = 0; d < 32; d++) Vt[d * VS + m] = tmp[d];
    } else {
#pragma unroll
      for (int d = 0; d < 32; d++) Vt[d * VS + m] = 0;
    }
  }

  // S = (Q*scale) K^T : 16 MFMAs
  const f32x4 fzero = {0.f, 0.f, 0.f, 0.f};
  f32x4 s[4][4];
#pragma unroll
  for (int i = 0; i < 4; i++)
#pragma unroll
    for (int j = 0; j < 4; j++)
      s[i][j] = __builtin_amdgcn_mfma_f32_16x16x32_bf16(aq[i], bk[j], fzero, 0, 0, 0);

  // bias + mask + row softmax (rows live on 16 lanes sharing quad; shfl-xor 1/2/4/8)
  const float* mrow = mask + (size_t)(b & 63) * (WIN_N * WIN_N);
#pragma unroll
  for (int i = 0; i < 4; i++) {
#pragma unroll
    for (int r = 0; r < 4; r++) {
      const int t = i * 16 + quad * 4 + r;
      const int ti = t / 7, tj = t % 7;
      float v[4];
#pragma unroll
      for (int j = 0; j < 4; j++) {
        const int m = j * 16 + l16;
        float x = s[i][j][r];
        if (t < WIN_N && m < WIN_N) {
          const int mi = m / 7, mj = m % 7;
          const int idx = (tj - mj + 6) * 13 + (ti - mi + 6);
          x += bias_table[idx * NH + h] + mrow[t * WIN_N + m];
        }
        if (m >= WIN_N) x = -3.0e38f;  // pad cols vanish in softmax
        v[j] = x;
      }
      float mx = fmaxf(fmaxf(v[0], v[1]), fmaxf(v[2], v[3]));
      mx = fmaxf(mx, __shfl_xor(mx, 1));
      mx = fmaxf(mx, __shfl_xor(mx, 2));
      mx = fmaxf(mx, __shfl_xor(mx, 4));
      mx = fmaxf(mx, __shfl_xor(mx, 8));
      float p[4];
      float sum = 0.f;
#pragma unroll
      for (int j = 0; j < 4; j++) {
        p[j] = __expf(v[j] - mx);
        sum += p[j];
      }
      sum += __shfl_xor(sum, 1);
      sum += __shfl_xor(sum, 2);
      sum += __shfl_xor(sum, 4);
      sum += __shfl_xor(sum, 8);
      const float inv = 1.0f / sum;
#pragma unroll
      for (int j = 0; j < 4; j++) Pl[t * PS + j * 16 + l16] = f2bf(p[j] * inv);
    }
  }
  __syncthreads();  // P,Vt (per-wave regions) ordered before frag reads

  // O = P V : P re-read in A-layout from LDS, Vt is the B^T operand
  f32x4 o[4][2];
#pragma unroll
  for (int i = 0; i < 4; i++)
#pragma unroll
    for (int ni = 0; ni < 2; ni++) o[i][ni] = fzero;
#pragma unroll
  for (int ki = 0; ki < 2; ki++) {
    bf16x8 bv[2];
#pragma unroll
    for (int ni = 0; ni < 2; ni++)
      bv[ni] = *(const bf16x8*)&Vt[(ni * 16 + l16) * VS + ki * 32 + quad * 8];
#pragma unroll
    for (int i = 0; i < 4; i++) {
      bf16x8 ap = *(const bf16x8*)&Pl[(i * 16 + l16) * PS + ki * 32 + quad * 8];
#pragma unroll
      for (int ni = 0; ni < 2; ni++)
        o[i][ni] = __builtin_amdgcn_mfma_f32_16x16x32_bf16(ap, bv[ni], o[i][ni], 0, 0, 0);
    }
  }

  // store O into this head's Q columns (bf16), rows t<49 only
#pragma unroll
  for (int i = 0; i < 4; i++) {
#pragma unroll
    for (int r = 0; r < 4; r++) {
      const int t = i * 16 + quad * 4 + r;
      if (t < WIN_N) {
        unsigned short* po = qkv + (row0 + t) * QKV_N + h * HD;
        po[l16] = f2bf(o[i][0][r]);
        po[16 + l16] = f2bf(o[i][1][r]);
      }
    }
  }
}

extern "C" void kernel_launch(void* const* d_in, const int* in_sizes, int n_in,
                              void* d_out, int out_size, void* d_ws, size_t ws_size,
                              hipStream_t stream) {
  const float* x = (const float*)d_in[0];
  const float* mask = (const float*)d_in[1];
  const float* qkv_w = (const float*)d_in[2];
  const float* qkv_b = (const float*)d_in[3];
  const float* proj_w = (const float*)d_in[4];
  const float* proj_b = (const float*)d_in[5];
  const float* bias_table = (const float*)d_in[6];
  float* out = (float*)d_out;

  // workspace: qkv buffer (bf16, doubles as attention output in Q slots) + transposed weights
  unsigned short* qkvb = (unsigned short*)d_ws;                       // 200704*1536*2 = 616562688 B
  unsigned short* wqkv_t = qkvb + (size_t)M_ROWS * QKV_N;             // 1536*512*2
  unsigned short* wproj_t = wqkv_t + (size_t)QKV_N * CDIM;            // 512*512*2  (total ~619 MB)

  prep_weights<<<4096, 256, 0, stream>>>(qkv_w, proj_w, wqkv_t, wproj_t);

  // QKV: [200704x512]f32 @ [512x1536] -> bf16, scale Q cols, +qkv_b
  gemm_bt<true, false><<<dim3(QKV_N / 128, M_ROWS / 128), 256, 0, stream>>>(
      x, CDIM, wqkv_t, qkvb, QKV_N, qkv_b, CDIM, 512, SCALE_Q);

  // fused window attention
  attn_mfma<<<dim3(NB, NH / 4), 256, 0, stream>>>(qkvb, bias_table, mask);

  // proj: [200704x512]bf16 (stride 1536) @ [512x512] -> f32 out, +proj_b
  gemm_bt<false, true><<<dim3(CDIM / 128, M_ROWS / 128), 256, 0, stream>>>(
      qkvb, QKV_N, wproj_t, out, CDIM, proj_b, CDIM, 0, 1.0f);
}